// Round 6
// baseline (42.093 us; speedup 1.0000x reference)
//
#include <hip/hip_runtime.h>
#include <stdint.h>

#define NROWS 8192
#define NDIM 128
#define NCLS 100
#define LCAP 512                    // per-class list capacity (n_c ~ 82 +- 9)

typedef short s16x8 __attribute__((ext_vector_type(8)));
typedef float f32x4 __attribute__((ext_vector_type(4)));

// ws byte offsets
#define WS_LIST 0u          // NCLS*LCAP int = 200 KB
#define WS_LCNT 0x40000u    // NCLS int
#define WS_SLOT 0x41000u    // NCLS float4 {prelu, spos, n, anchor}
#define WS_GC   0x42000u    // NCLS x 128 f32 per-class sum of f_hat

__device__ __forceinline__ uint32_t f32_to_bf16_rne(float x) {
    uint32_t u = __float_as_uint(x);
    return (u + 0x7FFFu + ((u >> 16) & 1u)) >> 16;
}

// One block per class: scan labels -> row list -> gather+normalize f32 rows
// directly into a swizzled bf16 LDS tile -> MFMA pairwise -> per-class sums.
__global__ __launch_bounds__(256) void kA_classes(const float* __restrict__ feat,
                                                  const int* __restrict__ labels,
                                                  char* __restrict__ ws) {
    __shared__ __align__(16) char sm[65536];  // tile A [0,32K), tile B [32K,64K)
    int tid = threadIdx.x;
    int lane = tid & 63, wave = tid >> 6;
    int c = blockIdx.x;

    int* lcnt = (int*)(ws + WS_LCNT) + c;
    if (tid == 0) __hip_atomic_store(lcnt, 0, __ATOMIC_RELAXED, __HIP_MEMORY_SCOPE_AGENT);
    // int64-label detect (per-wave ballot, no LDS): values 0..99 -> high words zero
    unsigned long long bl = __ballot(labels[2 * lane + 1] != 0);
    int shl = (bl == 0ull) ? 1 : 0;
    __syncthreads();

    // ---- scan all labels, build this class's row list ----
    int* list = (int*)(ws + WS_LIST) + c * LCAP;
    int labv[32];
#pragma unroll
    for (int r = 0; r < 32; ++r) labv[r] = labels[(r * 256 + tid) << shl];
#pragma unroll
    for (int r = 0; r < 32; ++r) {
        if (labv[r] == c) {
            int p = atomicAdd(lcnt, 1);
            if (p < LCAP) list[p] = r * 256 + tid;
        }
    }
    __syncthreads();
    int nfull = __hip_atomic_load(lcnt, __ATOMIC_RELAXED, __HIP_MEMORY_SCOPE_AGENT);
    int n = nfull > LCAP ? LCAP : nfull;

    const float4* feat4 = (const float4*)feat;
    int grp = tid >> 5;       // 8 row-groups (half-wave per row)
    int sl = tid & 31;        // lane-in-group: dims 4*sl..4*sl+3
    float gcp0 = 0.f, gcp1 = 0.f, gcp2 = 0.f, gcp3 = 0.f, aa = 0.f;
    float prelu = 0.f, spos = 0.f;
    int wm = wave >> 1, wn = wave & 1;
    int ntiles = (n + 127) >> 7;

    for (int ti = 0; ti < ntiles; ++ti)
        for (int tj = 0; tj <= ti; ++tj) {
            int rows_a = n - ti * 128; if (rows_a > 128) rows_a = 128;
            int rows_b = n - tj * 128; if (rows_b > 128) rows_b = 128;
            bool same = (ti == tj);
            __syncthreads();   // previous pair's MFMA reads complete
            // ---- fill tile(s): gather f32 rows, normalize, bf16, swizzled ds_write ----
            for (int sel = 0; sel < 2; ++sel) {
                if (sel == 1 && same) break;
                char* base = sel ? (sm + 32768) : sm;
                int t0 = sel ? tj * 128 : ti * 128;
                int rows = sel ? rows_b : rows_a;
                bool gcon = (sel == 0) && (tj == 0);  // each tile gc-counted once
                int passes = (rows + 7) >> 3;         // 8 rows in flight per pass
                for (int p0 = 0; p0 < passes; p0 += 4) {
                    float4 v[4]; int rrl[4];
#pragma unroll
                    for (int q = 0; q < 4; ++q) {
                        int rr = (p0 + q) * 8 + grp;
                        rrl[q] = rr;
                        int idx = t0 + ((rr < rows) ? rr : 0);
                        v[q] = feat4[list[idx] * 32 + sl];
                    }
#pragma unroll
                    for (int q = 0; q < 4; ++q) {
                        int rr = rrl[q];
                        float4 x = v[q];
                        float ss = x.x * x.x + x.y * x.y + x.z * x.z + x.w * x.w;
#pragma unroll
                        for (int o = 16; o; o >>= 1) ss += __shfl_xor(ss, o);
                        float sc = 1.0f / fmaxf(sqrtf(ss), 1e-12f);
                        float f0 = x.x * sc, f1 = x.y * sc, f2 = x.z * sc, f3 = x.w * sc;
                        if (gcon && rr < rows) {
                            gcp0 += f0; gcp1 += f1; gcp2 += f2; gcp3 += f3;
                            aa += (sl == 0) ? ss * sc * sc : 0.f;  // ||f_hat||^2 once/row
                        }
                        if (rr < 128) {
                            uint32_t lo = (f32_to_bf16_rne(f1) << 16) | f32_to_bf16_rne(f0);
                            uint32_t hi = (f32_to_bf16_rne(f3) << 16) | f32_to_bf16_rne(f2);
                            uint32_t ad = (uint32_t)(rr * 256) +
                                          (uint32_t)((sl * 8) ^ ((rr & 7) << 4));
                            *(uint64_t*)(base + ad) = ((uint64_t)hi << 32) | lo;
                        }
                    }
                }
            }
            __syncthreads();
            // ---- MFMA 128x128 (2x2 wave grid) + fused epilogue ----
            const char* bbase = same ? sm : (sm + 32768);
            int rb_ = lane & 15;
            uint32_t kcol = (uint32_t)((lane >> 4) << 4);
            f32x4 acc[4][4];
#pragma unroll
            for (int mi = 0; mi < 4; ++mi)
#pragma unroll
                for (int ni = 0; ni < 4; ++ni) acc[mi][ni] = f32x4{0.f, 0.f, 0.f, 0.f};
#pragma unroll
            for (int ks = 0; ks < 4; ++ks) {
                uint32_t c2 = (uint32_t)(ks * 64) + kcol;
                s16x8 a[4], b[4];
#pragma unroll
                for (int mi = 0; mi < 4; ++mi) {
                    int r = wm * 64 + mi * 16 + rb_;
                    uint32_t ad = (uint32_t)(r * 256) + (c2 ^ (uint32_t)((r & 7) << 4));
                    a[mi] = *reinterpret_cast<const s16x8*>(sm + ad);
                }
#pragma unroll
                for (int ni = 0; ni < 4; ++ni) {
                    int r = wn * 64 + ni * 16 + rb_;
                    uint32_t ad = (uint32_t)(r * 256) + (c2 ^ (uint32_t)((r & 7) << 4));
                    b[ni] = *reinterpret_cast<const s16x8*>(bbase + ad);
                }
#pragma unroll
                for (int mi = 0; mi < 4; ++mi)
#pragma unroll
                    for (int ni = 0; ni < 4; ++ni)
                        acc[mi][ni] = __builtin_amdgcn_mfma_f32_16x16x32_bf16(
                            a[mi], b[ni], acc[mi][ni], 0, 0, 0);
            }
            float tw = same ? 1.f : 2.f;   // off-diagonal tile pairs count twice
#pragma unroll
            for (int ni = 0; ni < 4; ++ni) {
                int jp = tj * 128 + wn * 64 + ni * 16 + rb_;
#pragma unroll
                for (int mi = 0; mi < 4; ++mi)
#pragma unroll
                    for (int rr = 0; rr < 4; ++rr) {
                        int ip = ti * 128 + wm * 64 + mi * 16 + ((lane >> 4) << 2) + rr;
                        bool vld = (ip < n) && (jp < n) && (ip != jp);
                        float s = acc[mi][ni][rr];
                        prelu += vld ? tw * fmaxf(fmaf(10.f, s, -9.f), 0.f) : 0.f;
                        spos  += vld ? tw * s : 0.f;
                    }
            }
        }

    // ---- block reductions (tiles dead; reuse sm) ----
#pragma unroll
    for (int o = 32; o; o >>= 1) {
        prelu += __shfl_xor(prelu, o);
        spos  += __shfl_xor(spos, o);
        aa    += __shfl_xor(aa, o);
    }
    __syncthreads();
    // gc: 8 groups x 128 dims; group g writes its float4 partial at sm + g*512 + sl*16
    float* gbuf = (float*)sm;
    *(float4*)(sm + grp * 512 + sl * 16) = float4{gcp0, gcp1, gcp2, gcp3};
    float* rs = (float*)(sm + 4096);
    if (lane == 0) { rs[wave * 3] = prelu; rs[wave * 3 + 1] = spos; rs[wave * 3 + 2] = aa; }
    __syncthreads();
    if (tid < NDIM) {   // dim t lives at byte 4*t within each group's 512B row
        float gsum = 0.f;
#pragma unroll
        for (int g = 0; g < 8; ++g) gsum += gbuf[g * 128 + tid];
        ((float*)(ws + WS_GC))[c * 128 + tid] = gsum;
    }
    if (tid == 0) {
        float4* slot = (float4*)(ws + WS_SLOT);
        slot[c] = float4{rs[0] + rs[3] + rs[6] + rs[9],
                         rs[1] + rs[4] + rs[7] + rs[10],
                         (float)nfull,
                         rs[2] + rs[5] + rs[8] + rs[11]};
    }
}

// One block: combine 100 slots + 100 per-class g vectors -> loss scalar.
// Kernel boundary = device-wide fence, so plain loads are safe.
__global__ __launch_bounds__(256) void kB_final(const char* __restrict__ ws,
                                                float* __restrict__ out) {
    __shared__ float sred[20];
    int tid = threadIdx.x, lane = tid & 63, wave = tid >> 6;
    const float4* slot = (const float4*)(ws + WS_SLOT);
    float pr = 0.f, sp = 0.f, sn2 = 0.f, sa = 0.f;
    if (tid < NCLS) {
        float4 s = slot[tid];
        pr = s.x; sp = s.y; sn2 = s.z * s.z; sa = s.w;
    }
    const float* gc = (const float*)(ws + WS_GC);
    float gs = 0.f;
    if (tid < NDIM) {
#pragma unroll 10
        for (int c = 0; c < NCLS; ++c) gs += gc[c * 128 + tid];
    }
    float g2 = gs * gs;
#pragma unroll
    for (int o = 32; o; o >>= 1) {
        pr += __shfl_xor(pr, o); sp += __shfl_xor(sp, o);
        sn2 += __shfl_xor(sn2, o); sa += __shfl_xor(sa, o);
        g2 += __shfl_xor(g2, o);
    }
    if (lane == 0) {
        sred[wave * 5] = pr; sred[wave * 5 + 1] = sp; sred[wave * 5 + 2] = sn2;
        sred[wave * 5 + 3] = sa; sred[wave * 5 + 4] = g2;
    }
    __syncthreads();
    if (tid == 0) {
        double prt = 0, spt = 0, sn2t = 0, sat = 0, g2t = 0;
#pragma unroll
        for (int w = 0; w < 4; ++w) {
            prt += sred[w * 5]; spt += sred[w * 5 + 1]; sn2t += sred[w * 5 + 2];
            sat += sred[w * 5 + 3]; g2t += sred[w * 5 + 4];
        }
        double count = 8192.0 * 8191.0;
        double nposoff = sn2t - 8192.0;
        double nneg = count - nposoff;
        double sall = g2t - sat;          // sum_{i != j} s_ij
        double sneg = sall - spt;
        double loss = (prt + 11.0 * nneg - 10.0 * sneg) / count;
        out[0] = (float)loss;
    }
}

extern "C" void kernel_launch(void* const* d_in, const int* in_sizes, int n_in,
                              void* d_out, int out_size, void* d_ws, size_t ws_size,
                              hipStream_t stream) {
    const float* feat = (const float*)d_in[0];
    const int* labels = (const int*)d_in[1];
    float* out = (float*)d_out;
    char* ws = (char*)d_ws;

    kA_classes<<<NCLS, 256, 0, stream>>>(feat, labels, ws);
    kB_final<<<1, 256, 0, stream>>>(ws, out);
}